// Round 1
// baseline (296.622 us; speedup 1.0000x reference)
//
#include <hip/hip_runtime.h>

// LatentTexture: quantize-STE (8b hi / 4b lo) + align_corners bilinear sample.
// Two-pass through d_ws:
//   pass 1: streaming quantize + channel-last u8 repack, 4 px/thread with
//           float4 NT loads (16B/lane = BW sweet spot, 4x fewer VMEM instrs
//           than R4's scalar loads), uint4 stores (L2 write-merged)
//   pass 2: 2 lanes/sample split by y-row: each lane loads its row's two
//           adjacent texels (x0,x1 same cache line), x-blends in-lane,
//           one __shfl_xor(.,1)/channel y-blends, lane t stores ch[8t..8t+8)
//           -> consecutive 32B segments, 2x waves vs 1 thread/sample.
// History: R1 direct 311; R2 4px-repack(no NT) 308.6; R4 1px+NT 292.4;
//          R5 quad-split+no-NT 298.9; R6(this) = 4px float4 NT loads.
// dur_us carries ~185us of in-stream harness restore/poison overhead
// (768MiB ws poison fill ~121us + input restore).

#define NSAMP   131072
#define HI_W    2048
#define LO_W    512
#define HI_PIX  (HI_W * HI_W)            // 4,194,304
#define LO_PIX  (LO_W * LO_W)            // 262,144
#define HI_PX4_BLOCKS (HI_PIX / 1024)    // 4096   (4 px/thread)
#define LO_PX4_BLOCKS (LO_PIX / 1024)    // 256
#define WS_NEED ((size_t)HI_PIX * 16 + (size_t)LO_PIX * 4)

typedef float fx4 __attribute__((ext_vector_type(4)));   // NT-load/store-compatible

__device__ __forceinline__ unsigned int quant_u(float v, float qmax) {
    return (unsigned int)rintf(fminf(fmaxf(v, 0.0f), 1.0f) * qmax);
}

// ---- Pass 1: quantize + transpose to channel-last u8, 4 px/thread ----------
__global__ __launch_bounds__(256)
void quant_pack_kernel(const float* __restrict__ hi,     // [12][HI_PIX]
                       const float* __restrict__ lo,     // [4][LO_PIX]
                       uint4* __restrict__ hiT,          // [HI_PIX]
                       unsigned int* __restrict__ loT)   // [LO_PIX]
{
    const int b = blockIdx.x;
    if (b < HI_PX4_BLOCKS) {
        const int p4 = (b * 256 + threadIdx.x) * 4;      // 16B-aligned f32 base
        unsigned int w[4][3] = {{0,0,0},{0,0,0},{0,0,0},{0,0,0}};
        #pragma unroll
        for (int c = 0; c < 12; ++c) {
            const fx4 v = __builtin_nontemporal_load(
                (const fx4*)(hi + (size_t)c * HI_PIX + p4));
            const int wi = c >> 2, sh = (c & 3) * 8;
            #pragma unroll
            for (int k = 0; k < 4; ++k)
                w[k][wi] |= quant_u(v[k], 255.0f) << sh;
        }
        #pragma unroll
        for (int k = 0; k < 4; ++k)
            hiT[p4 + k] = make_uint4(w[k][0], w[k][1], w[k][2], 0u);
    } else {
        const int p4 = ((b - HI_PX4_BLOCKS) * 256 + threadIdx.x) * 4;
        unsigned int w[4] = {0,0,0,0};
        #pragma unroll
        for (int c = 0; c < 4; ++c) {
            const fx4 v = __builtin_nontemporal_load(
                (const fx4*)(lo + (size_t)c * LO_PIX + p4));
            const int sh = c * 8;
            #pragma unroll
            for (int k = 0; k < 4; ++k)
                w[k] |= quant_u(v[k], 15.0f) << sh;
        }
        *(uint4*)(loT + p4) = make_uint4(w[0], w[1], w[2], w[3]);  // coalesced 16B
    }
}

// ---- Pass 2: bilinear sample, 2 lanes per sample (lane = y-row) ------------
__global__ __launch_bounds__(256)
void sample_kernel(const float2* __restrict__ uv,
                   const uint4* __restrict__ hiT,
                   const unsigned int* __restrict__ loT,
                   fx4* __restrict__ out)
{
    const int tid = blockIdx.x * 256 + threadIdx.x;
    const int s = tid >> 1;        // sample
    const int t = tid & 1;         // y-tap (0 -> y0 row, 1 -> y1 row)

    const float2 p = uv[s];        // pair-broadcast

    // ---------- hi coords (2048x2048) ----------
    const float gxh = p.x * 2.0f - 1.0f, gyh = p.y * 2.0f - 1.0f;
    const float ixh = (gxh + 1.0f) * 0.5f * (float)(HI_W - 1);
    const float iyh = (gyh + 1.0f) * 0.5f * (float)(HI_W - 1);
    const float ixh0f = floorf(ixh), iyh0f = floorf(iyh);
    const float wxh = ixh - ixh0f, wyh = iyh - iyh0f;
    int ixh0 = min(max((int)ixh0f, 0), HI_W - 1);
    int iyh0 = min(max((int)iyh0f, 0), HI_W - 1);
    const int ixh1 = min(ixh0 + 1, HI_W - 1);
    const int iyh1 = min(iyh0 + 1, HI_W - 1);
    const int ysh = t ? iyh1 : iyh0;
    const float wyf_h = t ? wyh : 1.0f - wyh;

    // ---------- lo coords (512x512) ----------
    const float ixl = (gxh + 1.0f) * 0.5f * (float)(LO_W - 1);
    const float iyl = (gyh + 1.0f) * 0.5f * (float)(LO_W - 1);
    const float ixl0f = floorf(ixl), iyl0f = floorf(iyl);
    const float wxl = ixl - ixl0f, wyl = iyl - iyl0f;
    int ixl0 = min(max((int)ixl0f, 0), LO_W - 1);
    int iyl0 = min(max((int)iyl0f, 0), LO_W - 1);
    const int ixl1 = min(ixl0 + 1, LO_W - 1);
    const int iyl1 = min(iyl0 + 1, LO_W - 1);
    const int ysl = t ? iyl1 : iyl0;
    const float wyf_l = t ? wyl : 1.0f - wyl;

    // issue all 4 scattered loads up front (x-pairs are line-adjacent)
    const uint4 a0 = hiT[(size_t)ysh * HI_W + ixh0];
    const uint4 a1 = hiT[(size_t)ysh * HI_W + ixh1];
    const unsigned int l0 = loT[ysl * LO_W + ixl0];
    const unsigned int l1 = loT[ysl * LO_W + ixl1];

    float r[16];
    {
        const unsigned int u0[3] = {a0.x, a0.y, a0.z};
        const unsigned int u1[3] = {a1.x, a1.y, a1.z};
        const float omwx = 1.0f - wxh;
        #pragma unroll
        for (int c = 0; c < 12; ++c) {
            const int w = c >> 2, sh = (c & 3) * 8;
            const float v0 = (float)((u0[w] >> sh) & 0xff);
            const float v1 = (float)((u1[w] >> sh) & 0xff);
            r[c] = wyf_h * (v0 * omwx + v1 * wxh);
        }
    }
    {
        const float omwx = 1.0f - wxl;
        #pragma unroll
        for (int c = 0; c < 4; ++c) {
            const int sh = c * 8;
            const float v0 = (float)((l0 >> sh) & 0xff);
            const float v1 = (float)((l1 >> sh) & 0xff);
            r[12 + c] = wyf_l * (v0 * omwx + v1 * wxl);
        }
    }

    // y-blend across the lane pair: one shuffle per channel
    #pragma unroll
    for (int j = 0; j < 16; ++j)
        r[j] += __shfl_xor(r[j], 1);

    // lane t stores channels [8t, 8t+8): two consecutive fx4 -> coalesced 32B
    const int base = 8 * t;
    fx4 v0, v1;
    #pragma unroll
    for (int j = 0; j < 4; ++j) {
        const int c0 = base + j, c1 = base + 4 + j;
        v0[j] = r[c0] * ((c0 < 12) ? (1.0f / 255.0f) : (1.0f / 15.0f));
        v1[j] = r[c1] * ((c1 < 12) ? (1.0f / 255.0f) : (1.0f / 15.0f));
    }
    __builtin_nontemporal_store(v0, &out[(size_t)tid * 2]);
    __builtin_nontemporal_store(v1, &out[(size_t)tid * 2 + 1]);
}

// ---- Fallback (round-1 direct kernel) if ws is unexpectedly small ----------
__global__ __launch_bounds__(256)
void direct_kernel(const float2* __restrict__ uv,
                   const float*  __restrict__ hi,
                   const float*  __restrict__ lo,
                   float*        __restrict__ out)
{
    const int tid = blockIdx.x * 256 + threadIdx.x;
    const int s = tid >> 4, c = tid & 15;
    const float2 p = uv[s];
    const float* tex; int W; float qmax, rq;
    if (c < 12) { tex = hi + (size_t)c * HI_PIX; W = HI_W; qmax = 255.0f; rq = 1.0f/255.0f; }
    else        { tex = lo + (size_t)(c-12) * LO_PIX; W = LO_W; qmax = 15.0f; rq = 1.0f/15.0f; }
    const float gx = p.x * 2.0f - 1.0f, gy = p.y * 2.0f - 1.0f;
    const float ix = (gx + 1.0f) * 0.5f * (float)(W - 1);
    const float iy = (gy + 1.0f) * 0.5f * (float)(W - 1);
    const float ix0f = floorf(ix), iy0f = floorf(iy);
    const float wx = ix - ix0f, wy = iy - iy0f;
    int ix0 = min(max((int)ix0f, 0), W - 1);
    int iy0 = min(max((int)iy0f, 0), W - 1);
    const int ix1 = min(ix0 + 1, W - 1), iy1 = min(iy0 + 1, W - 1);
    const float* r0 = tex + (size_t)iy0 * W;
    const float* r1 = tex + (size_t)iy1 * W;
    float v00 = rintf(fminf(fmaxf(r0[ix0],0.f),1.f)*qmax)*rq;
    float v01 = rintf(fminf(fmaxf(r0[ix1],0.f),1.f)*qmax)*rq;
    float v10 = rintf(fminf(fmaxf(r1[ix0],0.f),1.f)*qmax)*rq;
    float v11 = rintf(fminf(fmaxf(r1[ix1],0.f),1.f)*qmax)*rq;
    out[(size_t)s*16 + c] = v00*(1.f-wy)*(1.f-wx) + v01*(1.f-wy)*wx
                          + v10*wy*(1.f-wx)       + v11*wy*wx;
}

extern "C" void kernel_launch(void* const* d_in, const int* in_sizes, int n_in,
                              void* d_out, int out_size, void* d_ws, size_t ws_size,
                              hipStream_t stream) {
    const float2* uv = (const float2*)d_in[0];
    const float*  hi = (const float*)d_in[1];
    const float*  lo = (const float*)d_in[2];
    float* out = (float*)d_out;

    if (ws_size < WS_NEED) {
        direct_kernel<<<(NSAMP * 16) / 256, 256, 0, stream>>>(uv, hi, lo, out);
        return;
    }

    uint4* hiT = (uint4*)d_ws;                                   // 64 MiB
    unsigned int* loT = (unsigned int*)((char*)d_ws + (size_t)HI_PIX * 16);  // 1 MiB

    quant_pack_kernel<<<HI_PX4_BLOCKS + LO_PX4_BLOCKS, 256, 0, stream>>>(hi, lo, hiT, loT);
    sample_kernel<<<(NSAMP * 2) / 256, 256, 0, stream>>>(uv, hiT, loT, (fx4*)out);
}

// Round 2
// 295.618 us; speedup vs baseline: 1.0034x; 1.0034x over previous
//
#include <hip/hip_runtime.h>

// LatentTexture: quantize-STE (8b hi / 4b lo) + align_corners bilinear sample.
// Two-pass through d_ws:
//   pass 1: streaming quantize + channel-last u8 repack, 4 px/thread with
//           float4 NT loads (16B/lane), LDS-transposed so stores stay
//           1 px/lane uint4 (1KB dense per instruction, the R4 pattern).
//           LDS slot swizzle s(px)=px^((px>>2)&31) -> conflict-free b128
//           writes AND reads (each bank gets exactly 8 dwords/wave = min).
//   pass 2: 2 lanes/sample split by y-row: each lane loads its row's two
//           adjacent texels (x0,x1 same cache line), x-blends in-lane,
//           one __shfl_xor(.,1)/channel y-blends, lane t stores ch[8t..8t+8)
//           -> consecutive 32B segments.
// History: R1 direct 311; R2 4px-repack(no NT) 308.6; R4 1px+NT 292.4 /
//          290.2; R5 quad-split 298.9; R6 4px f4-loads+strided stores 296.6
//          (strided 64B-stride uint4 stores = 25%-dense instrs regressed);
//          R7(this) = f4 loads + LDS transpose + dense stores.
// dur_us carries ~185us of in-stream harness restore/poison overhead
// (768MiB ws poison fill ~121us each + input restore).

#define NSAMP   131072
#define HI_W    2048
#define LO_W    512
#define HI_PIX  (HI_W * HI_W)            // 4,194,304
#define LO_PIX  (LO_W * LO_W)            // 262,144
#define HI_PX4_BLOCKS (HI_PIX / 1024)    // 4096   (1024 px/block, 4 px/thread)
#define LO_PX4_BLOCKS (LO_PIX / 1024)    // 256
#define WS_NEED ((size_t)HI_PIX * 16 + (size_t)LO_PIX * 4)

typedef float fx4 __attribute__((ext_vector_type(4)));   // NT-load/store-compatible

__device__ __forceinline__ unsigned int quant_u(float v, float qmax) {
    return (unsigned int)rintf(fminf(fmaxf(v, 0.0f), 1.0f) * qmax);
}

// ---- Pass 1: quantize + transpose to channel-last u8 -----------------------
// Loads: float4 NT (16B/lane, coalesced). Stores: 1 px/lane (dense).
// LDS transpose bridges the two layouts; XOR swizzle keeps banks uniform.
__global__ __launch_bounds__(256)
void quant_pack_kernel(const float* __restrict__ hi,     // [12][HI_PIX]
                       const float* __restrict__ lo,     // [4][LO_PIX]
                       uint4* __restrict__ hiT,          // [HI_PIX]
                       unsigned int* __restrict__ loT)   // [LO_PIX]
{
    __shared__ uint4 lds4[1024];                         // 16 KiB
    const int t = threadIdx.x;
    const int b = blockIdx.x;

    if (b < HI_PX4_BLOCKS) {
        const int base = b * 1024;
        unsigned int w[4][3] = {{0,0,0},{0,0,0},{0,0,0},{0,0,0}};
        #pragma unroll
        for (int c = 0; c < 12; ++c) {
            const fx4 v = __builtin_nontemporal_load(
                (const fx4*)(hi + (size_t)c * HI_PIX + base + t * 4));
            const int wi = c >> 2, sh = (c & 3) * 8;
            #pragma unroll
            for (int k = 0; k < 4; ++k)
                w[k][wi] |= quant_u(v[k], 255.0f) << sh;
        }
        // LDS write: b128 per px at swizzled slot (conflict-free, see header)
        #pragma unroll
        for (int k = 0; k < 4; ++k) {
            const int px = t * 4 + k;
            const int s  = px ^ ((px >> 2) & 31);        // = px ^ (t & 31)
            lds4[s] = make_uint4(w[k][0], w[k][1], w[k][2], 0u);
        }
        __syncthreads();
        // store rounds: lane t owns px r*256+t -> 16B/lane dense uint4 store
        #pragma unroll
        for (int r = 0; r < 4; ++r) {
            const int px = r * 256 + t;
            const int s  = px ^ ((px >> 2) & 31);        // = px ^ ((t>>2) & 31)
            hiT[base + px] = lds4[s];
        }
    } else {
        const int base = (b - HI_PX4_BLOCKS) * 1024;
        unsigned int* ldsw = (unsigned int*)lds4;
        unsigned int w[4] = {0,0,0,0};
        #pragma unroll
        for (int c = 0; c < 4; ++c) {
            const fx4 v = __builtin_nontemporal_load(
                (const fx4*)(lo + (size_t)c * LO_PIX + base + t * 4));
            const int sh = c * 8;
            #pragma unroll
            for (int k = 0; k < 4; ++k)
                w[k] |= quant_u(v[k], 15.0f) << sh;
        }
        #pragma unroll
        for (int k = 0; k < 4; ++k) {
            const int px = t * 4 + k;
            const int s  = px ^ ((px >> 2) & 31);
            ldsw[s] = w[k];
        }
        __syncthreads();
        #pragma unroll
        for (int r = 0; r < 4; ++r) {
            const int px = r * 256 + t;
            const int s  = px ^ ((px >> 2) & 31);
            loT[base + px] = ldsw[s];                    // 4B/lane dense
        }
    }
}

// ---- Pass 2: bilinear sample, 2 lanes per sample (lane = y-row) ------------
__global__ __launch_bounds__(256)
void sample_kernel(const float2* __restrict__ uv,
                   const uint4* __restrict__ hiT,
                   const unsigned int* __restrict__ loT,
                   fx4* __restrict__ out)
{
    const int tid = blockIdx.x * 256 + threadIdx.x;
    const int s = tid >> 1;        // sample
    const int t = tid & 1;         // y-tap (0 -> y0 row, 1 -> y1 row)

    const float2 p = uv[s];        // pair-broadcast

    // ---------- hi coords (2048x2048) ----------
    const float gxh = p.x * 2.0f - 1.0f, gyh = p.y * 2.0f - 1.0f;
    const float ixh = (gxh + 1.0f) * 0.5f * (float)(HI_W - 1);
    const float iyh = (gyh + 1.0f) * 0.5f * (float)(HI_W - 1);
    const float ixh0f = floorf(ixh), iyh0f = floorf(iyh);
    const float wxh = ixh - ixh0f, wyh = iyh - iyh0f;
    int ixh0 = min(max((int)ixh0f, 0), HI_W - 1);
    int iyh0 = min(max((int)iyh0f, 0), HI_W - 1);
    const int ixh1 = min(ixh0 + 1, HI_W - 1);
    const int iyh1 = min(iyh0 + 1, HI_W - 1);
    const int ysh = t ? iyh1 : iyh0;
    const float wyf_h = t ? wyh : 1.0f - wyh;

    // ---------- lo coords (512x512) ----------
    const float ixl = (gxh + 1.0f) * 0.5f * (float)(LO_W - 1);
    const float iyl = (gyh + 1.0f) * 0.5f * (float)(LO_W - 1);
    const float ixl0f = floorf(ixl), iyl0f = floorf(iyl);
    const float wxl = ixl - ixl0f, wyl = iyl - iyl0f;
    int ixl0 = min(max((int)ixl0f, 0), LO_W - 1);
    int iyl0 = min(max((int)iyl0f, 0), LO_W - 1);
    const int ixl1 = min(ixl0 + 1, LO_W - 1);
    const int iyl1 = min(iyl0 + 1, LO_W - 1);
    const int ysl = t ? iyl1 : iyl0;
    const float wyf_l = t ? wyl : 1.0f - wyl;

    // issue all 4 scattered loads up front (x-pairs are line-adjacent)
    const uint4 a0 = hiT[(size_t)ysh * HI_W + ixh0];
    const uint4 a1 = hiT[(size_t)ysh * HI_W + ixh1];
    const unsigned int l0 = loT[ysl * LO_W + ixl0];
    const unsigned int l1 = loT[ysl * LO_W + ixl1];

    float r[16];
    {
        const unsigned int u0[3] = {a0.x, a0.y, a0.z};
        const unsigned int u1[3] = {a1.x, a1.y, a1.z};
        const float omwx = 1.0f - wxh;
        #pragma unroll
        for (int c = 0; c < 12; ++c) {
            const int w = c >> 2, sh = (c & 3) * 8;
            const float v0 = (float)((u0[w] >> sh) & 0xff);
            const float v1 = (float)((u1[w] >> sh) & 0xff);
            r[c] = wyf_h * (v0 * omwx + v1 * wxh);
        }
    }
    {
        const float omwx = 1.0f - wxl;
        #pragma unroll
        for (int c = 0; c < 4; ++c) {
            const int sh = c * 8;
            const float v0 = (float)((l0 >> sh) & 0xff);
            const float v1 = (float)((l1 >> sh) & 0xff);
            r[12 + c] = wyf_l * (v0 * omwx + v1 * wxl);
        }
    }

    // y-blend across the lane pair: one shuffle per channel
    #pragma unroll
    for (int j = 0; j < 16; ++j)
        r[j] += __shfl_xor(r[j], 1);

    // lane t stores channels [8t, 8t+8): two consecutive fx4 -> coalesced 32B
    const int base = 8 * t;
    fx4 v0, v1;
    #pragma unroll
    for (int j = 0; j < 4; ++j) {
        const int c0 = base + j, c1 = base + 4 + j;
        v0[j] = r[c0] * ((c0 < 12) ? (1.0f / 255.0f) : (1.0f / 15.0f));
        v1[j] = r[c1] * ((c1 < 12) ? (1.0f / 255.0f) : (1.0f / 15.0f));
    }
    __builtin_nontemporal_store(v0, &out[(size_t)tid * 2]);
    __builtin_nontemporal_store(v1, &out[(size_t)tid * 2 + 1]);
}

// ---- Fallback (round-1 direct kernel) if ws is unexpectedly small ----------
__global__ __launch_bounds__(256)
void direct_kernel(const float2* __restrict__ uv,
                   const float*  __restrict__ hi,
                   const float*  __restrict__ lo,
                   float*        __restrict__ out)
{
    const int tid = blockIdx.x * 256 + threadIdx.x;
    const int s = tid >> 4, c = tid & 15;
    const float2 p = uv[s];
    const float* tex; int W; float qmax, rq;
    if (c < 12) { tex = hi + (size_t)c * HI_PIX; W = HI_W; qmax = 255.0f; rq = 1.0f/255.0f; }
    else        { tex = lo + (size_t)(c-12) * LO_PIX; W = LO_W; qmax = 15.0f; rq = 1.0f/15.0f; }
    const float gx = p.x * 2.0f - 1.0f, gy = p.y * 2.0f - 1.0f;
    const float ix = (gx + 1.0f) * 0.5f * (float)(W - 1);
    const float iy = (gy + 1.0f) * 0.5f * (float)(W - 1);
    const float ix0f = floorf(ix), iy0f = floorf(iy);
    const float wx = ix - ix0f, wy = iy - iy0f;
    int ix0 = min(max((int)ix0f, 0), W - 1);
    int iy0 = min(max((int)iy0f, 0), W - 1);
    const int ix1 = min(ix0 + 1, W - 1), iy1 = min(iy0 + 1, W - 1);
    const float* r0 = tex + (size_t)iy0 * W;
    const float* r1 = tex + (size_t)iy1 * W;
    float v00 = rintf(fminf(fmaxf(r0[ix0],0.f),1.f)*qmax)*rq;
    float v01 = rintf(fminf(fmaxf(r0[ix1],0.f),1.f)*qmax)*rq;
    float v10 = rintf(fminf(fmaxf(r1[ix0],0.f),1.f)*qmax)*rq;
    float v11 = rintf(fminf(fmaxf(r1[ix1],0.f),1.f)*qmax)*rq;
    out[(size_t)s*16 + c] = v00*(1.f-wy)*(1.f-wx) + v01*(1.f-wy)*wx
                          + v10*wy*(1.f-wx)       + v11*wy*wx;
}

extern "C" void kernel_launch(void* const* d_in, const int* in_sizes, int n_in,
                              void* d_out, int out_size, void* d_ws, size_t ws_size,
                              hipStream_t stream) {
    const float2* uv = (const float2*)d_in[0];
    const float*  hi = (const float*)d_in[1];
    const float*  lo = (const float*)d_in[2];
    float* out = (float*)d_out;

    if (ws_size < WS_NEED) {
        direct_kernel<<<(NSAMP * 16) / 256, 256, 0, stream>>>(uv, hi, lo, out);
        return;
    }

    uint4* hiT = (uint4*)d_ws;                                   // 64 MiB
    unsigned int* loT = (unsigned int*)((char*)d_ws + (size_t)HI_PIX * 16);  // 1 MiB

    quant_pack_kernel<<<HI_PX4_BLOCKS + LO_PX4_BLOCKS, 256, 0, stream>>>(hi, lo, hiT, loT);
    sample_kernel<<<(NSAMP * 2) / 256, 256, 0, stream>>>(uv, hiT, loT, (fx4*)out);
}

// Round 3
// 287.687 us; speedup vs baseline: 1.0311x; 1.0276x over previous
//
#include <hip/hip_runtime.h>

// LatentTexture: quantize-STE (8b hi / 4b lo) + align_corners bilinear sample.
// Two-pass through d_ws:
//   pass 1: streaming quantize + channel-last u8 repack, R4's proven load
//           side (1 px/thread, scalar NT loads = 256B/wave coalesced, 64k
//           waves) but 12B/px hiT records (uint4's 4th dword was wasted:
//           -16MiB write, -16MiB pass-2 footprint). 16B->12B layout bridged
//           by per-block LDS repack on the STORE side only: lds[3t+r]
//           (stride 3 coprime 32 banks = conflict-free), barrier, threads
//           0..191 ds_read_b128 + dense 16B store (block's 3072B contig).
//   pass 2: 2 lanes/sample split by y-row: each lane dwordx3-loads its
//           row's two adjacent 12B texels (line-adjacent), x-blends in-lane,
//           one __shfl_xor(.,1)/channel y-blends, lane t stores ch[8t..8t+8)
//           -> consecutive 32B segments.
// History: R1 direct 311; R2 4px-repack 308.6; R4 1px+NT+uint4 292.4/290.2
//          (best); R5 quad-split 298.9; R6 f4loads+strided 296.6; R7
//          f4loads+LDS 295.6. R6~=R7 despite different stores => the
//          f4-load/4px-thread change was the regression; store side neutral.
//          R8(this) = R4 loads + 12B records via store-side LDS repack.
// dur_us carries ~185us of in-stream harness restore/poison overhead
// (768MiB ws poison fill ~121us each + input restore).

#define NSAMP   131072
#define HI_W    2048
#define LO_W    512
#define HI_PIX  (HI_W * HI_W)            // 4,194,304
#define LO_PIX  (LO_W * LO_W)            // 262,144
#define HI_PX_BLOCKS (HI_PIX / 256)      // 16384  (1 px/thread)
#define LO_PX_BLOCKS (LO_PIX / 256)      // 1024
#define WS_NEED ((size_t)HI_PIX * 12 + (size_t)LO_PIX * 4)   // 49 MiB

typedef float fx4 __attribute__((ext_vector_type(4)));   // NT-store-compatible

__device__ __forceinline__ unsigned int quant_u(float v, float qmax) {
    return (unsigned int)rintf(fminf(fmaxf(v, 0.0f), 1.0f) * qmax);
}

// ---- Pass 1: quantize + transpose to channel-last u8, 1 px/thread ----------
__global__ __launch_bounds__(256)
void quant_pack_kernel(const float* __restrict__ hi,     // [12][HI_PIX]
                       const float* __restrict__ lo,     // [4][LO_PIX]
                       unsigned int* __restrict__ hiT,   // [HI_PIX*3] dwords
                       unsigned int* __restrict__ loT)   // [LO_PIX]
{
    __shared__ unsigned int lds[768];                    // 3 KiB: 256 px * 12B
    const int t = threadIdx.x;
    const int b = blockIdx.x;
    if (b < HI_PX_BLOCKS) {
        const int p = b * 256 + t;
        unsigned int w0 = 0, w1 = 0, w2 = 0;
        #pragma unroll
        for (int c = 0; c < 4; ++c)
            w0 |= quant_u(__builtin_nontemporal_load(hi + (size_t)c * HI_PIX + p), 255.0f) << (c * 8);
        #pragma unroll
        for (int c = 4; c < 8; ++c)
            w1 |= quant_u(__builtin_nontemporal_load(hi + (size_t)c * HI_PIX + p), 255.0f) << ((c - 4) * 8);
        #pragma unroll
        for (int c = 8; c < 12; ++c)
            w2 |= quant_u(__builtin_nontemporal_load(hi + (size_t)c * HI_PIX + p), 255.0f) << ((c - 8) * 8);
        // 12B/px into LDS; addr stride 3 dwords, gcd(3,32)=1 -> conflict-free
        lds[3 * t + 0] = w0;
        lds[3 * t + 1] = w1;
        lds[3 * t + 2] = w2;
        __syncthreads();
        // waves 0-2 store the block's 3072B contiguously, 16B/lane dense;
        // wave 3 idles (no intra-wave divergence)
        if (t < 192) {
            const uint4 v = *(const uint4*)&lds[4 * t];  // dense ds_read_b128
            *((uint4*)(hiT + (size_t)b * 768) + t) = v;  // 16B/lane, coalesced
        }
    } else {
        const int p = (b - HI_PX_BLOCKS) * 256 + t;
        unsigned int w = 0;
        #pragma unroll
        for (int c = 0; c < 4; ++c)
            w |= quant_u(__builtin_nontemporal_load(lo + (size_t)c * LO_PIX + p), 15.0f) << (c * 8);
        loT[p] = w;                                      // 4B/lane dense
    }
}

// ---- Pass 2: bilinear sample, 2 lanes per sample (lane = y-row) ------------
__global__ __launch_bounds__(256)
void sample_kernel(const float2* __restrict__ uv,
                   const unsigned int* __restrict__ hiT,  // 12B/px records
                   const unsigned int* __restrict__ loT,
                   fx4* __restrict__ out)
{
    const int tid = blockIdx.x * 256 + threadIdx.x;
    const int s = tid >> 1;        // sample
    const int t = tid & 1;         // y-tap (0 -> y0 row, 1 -> y1 row)

    const float2 p = uv[s];        // pair-broadcast

    // ---------- hi coords (2048x2048) ----------
    const float gxh = p.x * 2.0f - 1.0f, gyh = p.y * 2.0f - 1.0f;
    const float ixh = (gxh + 1.0f) * 0.5f * (float)(HI_W - 1);
    const float iyh = (gyh + 1.0f) * 0.5f * (float)(HI_W - 1);
    const float ixh0f = floorf(ixh), iyh0f = floorf(iyh);
    const float wxh = ixh - ixh0f, wyh = iyh - iyh0f;
    int ixh0 = min(max((int)ixh0f, 0), HI_W - 1);
    int iyh0 = min(max((int)iyh0f, 0), HI_W - 1);
    const int ixh1 = min(ixh0 + 1, HI_W - 1);
    const int iyh1 = min(iyh0 + 1, HI_W - 1);
    const int ysh = t ? iyh1 : iyh0;
    const float wyf_h = t ? wyh : 1.0f - wyh;

    // ---------- lo coords (512x512) ----------
    const float ixl = (gxh + 1.0f) * 0.5f * (float)(LO_W - 1);
    const float iyl = (gyh + 1.0f) * 0.5f * (float)(LO_W - 1);
    const float ixl0f = floorf(ixl), iyl0f = floorf(iyl);
    const float wxl = ixl - ixl0f, wyl = iyl - iyl0f;
    int ixl0 = min(max((int)ixl0f, 0), LO_W - 1);
    int iyl0 = min(max((int)iyl0f, 0), LO_W - 1);
    const int ixl1 = min(ixl0 + 1, LO_W - 1);
    const int iyl1 = min(iyl0 + 1, LO_W - 1);
    const int ysl = t ? iyl1 : iyl0;
    const float wyf_l = t ? wyl : 1.0f - wyl;

    // issue all scattered loads up front (x-pair records are line-adjacent)
    const unsigned int* h0 = hiT + 3 * ((size_t)ysh * HI_W + ixh0);
    const unsigned int* h1 = hiT + 3 * ((size_t)ysh * HI_W + ixh1);
    unsigned int u0[3], u1[3];
    u0[0] = h0[0]; u0[1] = h0[1]; u0[2] = h0[2];          // dwordx3
    u1[0] = h1[0]; u1[1] = h1[1]; u1[2] = h1[2];          // dwordx3
    const unsigned int l0 = loT[ysl * LO_W + ixl0];
    const unsigned int l1 = loT[ysl * LO_W + ixl1];

    float r[16];
    {
        const float omwx = 1.0f - wxh;
        #pragma unroll
        for (int c = 0; c < 12; ++c) {
            const int w = c >> 2, sh = (c & 3) * 8;
            const float v0 = (float)((u0[w] >> sh) & 0xff);
            const float v1 = (float)((u1[w] >> sh) & 0xff);
            r[c] = wyf_h * (v0 * omwx + v1 * wxh);
        }
    }
    {
        const float omwx = 1.0f - wxl;
        #pragma unroll
        for (int c = 0; c < 4; ++c) {
            const int sh = c * 8;
            const float v0 = (float)((l0 >> sh) & 0xff);
            const float v1 = (float)((l1 >> sh) & 0xff);
            r[12 + c] = wyf_l * (v0 * omwx + v1 * wxl);
        }
    }

    // y-blend across the lane pair: one shuffle per channel
    #pragma unroll
    for (int j = 0; j < 16; ++j)
        r[j] += __shfl_xor(r[j], 1);

    // lane t stores channels [8t, 8t+8): two consecutive fx4 -> coalesced 32B
    const int base = 8 * t;
    fx4 v0, v1;
    #pragma unroll
    for (int j = 0; j < 4; ++j) {
        const int c0 = base + j, c1 = base + 4 + j;
        v0[j] = r[c0] * ((c0 < 12) ? (1.0f / 255.0f) : (1.0f / 15.0f));
        v1[j] = r[c1] * ((c1 < 12) ? (1.0f / 255.0f) : (1.0f / 15.0f));
    }
    __builtin_nontemporal_store(v0, &out[(size_t)tid * 2]);
    __builtin_nontemporal_store(v1, &out[(size_t)tid * 2 + 1]);
}

// ---- Fallback (round-1 direct kernel) if ws is unexpectedly small ----------
__global__ __launch_bounds__(256)
void direct_kernel(const float2* __restrict__ uv,
                   const float*  __restrict__ hi,
                   const float*  __restrict__ lo,
                   float*        __restrict__ out)
{
    const int tid = blockIdx.x * 256 + threadIdx.x;
    const int s = tid >> 4, c = tid & 15;
    const float2 p = uv[s];
    const float* tex; int W; float qmax, rq;
    if (c < 12) { tex = hi + (size_t)c * HI_PIX; W = HI_W; qmax = 255.0f; rq = 1.0f/255.0f; }
    else        { tex = lo + (size_t)(c-12) * LO_PIX; W = LO_W; qmax = 15.0f; rq = 1.0f/15.0f; }
    const float gx = p.x * 2.0f - 1.0f, gy = p.y * 2.0f - 1.0f;
    const float ix = (gx + 1.0f) * 0.5f * (float)(W - 1);
    const float iy = (gy + 1.0f) * 0.5f * (float)(W - 1);
    const float ix0f = floorf(ix), iy0f = floorf(iy);
    const float wx = ix - ix0f, wy = iy - iy0f;
    int ix0 = min(max((int)ix0f, 0), W - 1);
    int iy0 = min(max((int)iy0f, 0), W - 1);
    const int ix1 = min(ix0 + 1, W - 1), iy1 = min(iy0 + 1, W - 1);
    const float* r0 = tex + (size_t)iy0 * W;
    const float* r1 = tex + (size_t)iy1 * W;
    float v00 = rintf(fminf(fmaxf(r0[ix0],0.f),1.f)*qmax)*rq;
    float v01 = rintf(fminf(fmaxf(r0[ix1],0.f),1.f)*qmax)*rq;
    float v10 = rintf(fminf(fmaxf(r1[ix0],0.f),1.f)*qmax)*rq;
    float v11 = rintf(fminf(fmaxf(r1[ix1],0.f),1.f)*qmax)*rq;
    out[(size_t)s*16 + c] = v00*(1.f-wy)*(1.f-wx) + v01*(1.f-wy)*wx
                          + v10*wy*(1.f-wx)       + v11*wy*wx;
}

extern "C" void kernel_launch(void* const* d_in, const int* in_sizes, int n_in,
                              void* d_out, int out_size, void* d_ws, size_t ws_size,
                              hipStream_t stream) {
    const float2* uv = (const float2*)d_in[0];
    const float*  hi = (const float*)d_in[1];
    const float*  lo = (const float*)d_in[2];
    float* out = (float*)d_out;

    if (ws_size < WS_NEED) {
        direct_kernel<<<(NSAMP * 16) / 256, 256, 0, stream>>>(uv, hi, lo, out);
        return;
    }

    unsigned int* hiT = (unsigned int*)d_ws;                                 // 48 MiB
    unsigned int* loT = (unsigned int*)((char*)d_ws + (size_t)HI_PIX * 12);  // 1 MiB

    quant_pack_kernel<<<HI_PX_BLOCKS + LO_PX_BLOCKS, 256, 0, stream>>>(hi, lo, hiT, loT);
    sample_kernel<<<(NSAMP * 2) / 256, 256, 0, stream>>>(uv, hiT, loT, (fx4*)out);
}